// Round 13
// baseline (239.048 us; speedup 1.0000x reference)
//
#include <hip/hip_runtime.h>
#include <stdint.h>

#define B 4096
#define D 2048
#define BK 128          // k-slab per barrier (fp8 elements; 128 B rows)

typedef unsigned long long ull;
typedef float f32x4 __attribute__((ext_vector_type(4)));

#define SENT_P 0x00000000FFFFFFFFull  // dist=0.0, ~idx -> "no positive seen"
#define SENT_N (~0ull)                // +inf      -> "no negative seen"

// ---------------- fp32 -> fp8 e4m3 (OCP) + norms + sentinel init ------------
__global__ void k_convert_sq(const float* __restrict__ emb,
                             unsigned char* __restrict__ embq,
                             float* __restrict__ sq,
                             float* __restrict__ rs,
                             ull* __restrict__ bp,
                             ull* __restrict__ bn) {
  const int row = blockIdx.x, t = threadIdx.x;
  const float4* src = (const float4*)(emb + (size_t)row * D);
  float4 v0 = src[2 * t], v1 = src[2 * t + 1];
  float s = v0.x * v0.x + v0.y * v0.y + v0.z * v0.z + v0.w * v0.w
          + v1.x * v1.x + v1.y * v1.y + v1.z * v1.z + v1.w * v1.w;
  float sm = v0.x + v0.y + v0.z + v0.w + v1.x + v1.y + v1.z + v1.w;

  unsigned w0 = __builtin_amdgcn_cvt_pk_fp8_f32(v0.x, v0.y, 0, false);
  w0 = __builtin_amdgcn_cvt_pk_fp8_f32(v0.z, v0.w, w0, true);
  unsigned w1 = __builtin_amdgcn_cvt_pk_fp8_f32(v1.x, v1.y, 0, false);
  w1 = __builtin_amdgcn_cvt_pk_fp8_f32(v1.z, v1.w, w1, true);
  uint2 o; o.x = w0; o.y = w1;
  ((uint2*)(embq + (size_t)row * D))[t] = o;

  for (int off = 32; off; off >>= 1) {
    s  += __shfl_down(s, off, 64);
    sm += __shfl_down(sm, off, 64);
  }
  __shared__ float ps[4], pm[4];
  int lane = t & 63, wave = t >> 6;
  if (lane == 0) { ps[wave] = s; pm[wave] = sm; }
  __syncthreads();
  if (t == 0) {
    sq[row] = ps[0] + ps[1] + ps[2] + ps[3];
    rs[row] = pm[0] + pm[1] + pm[2] + pm[3];
    bp[row] = SENT_P;
    bn[row] = SENT_N;
  }
}

// ---------------- fused symmetric fp8 GEMM + hard pos/neg selection ---------
// 64x128 tiles over the strict upper triangle (j > i): 1056 blocks,
// sequential triangular decode. R12's 2-wave shape (each wave: full 64 A
// rows x its 64-col B half, 4x4 16x16x32 fp8 MFMA frags, 64/wave/iter).
// NEW vs R12: register-prefetch software pipeline — slab k+1 is loaded
// global->VGPR (12 x uint4/thread) DURING slab k's compute, then written
// to the single 24KB LDS buffer next iteration. The vmcnt wait before
// ds_write covers loads issued a full compute-phase earlier -> K-loop no
// longer stalls on L2/L3 latency (the R8/R12 ~56us plateau: 7.3 TB/s
// effective vs 10.5 achievable = latency-bound, not BW-bound). LDS stays
// 24KB (R5's 2x-LDS dbuf occupancy trap avoided). VGPR ~145 under the
// (128,3) cap ~170 -> no spill (R9/R10 signature: WRITE_SIZE explosion).
// XOR chunk swizzle (slot = chunk ^ (row&7)) unchanged. No fences (R11).
__launch_bounds__(128, 3)
__global__ void k_gemm_select(const unsigned char* __restrict__ embq,
                              const float* __restrict__ sq,
                              const int* __restrict__ labels,
                              ull* __restrict__ best_pos,
                              ull* __restrict__ best_neg) {
  __shared__ unsigned char ldsA[64 * BK];    // 8 KB
  __shared__ unsigned char ldsB[128 * BK];   // 16 KB

  // linear bid -> (by in [0,64), bx in [0,32)) with bx*128+127 > by*64
  int rem = blockIdx.x, p = 0;
  while (rem >= 2 * (32 - p)) { rem -= 2 * (32 - p); ++p; }
  int by = 2 * p;
  int c = 32 - p;
  if (rem >= c) { by += 1; rem -= c; }
  const int bx = p + rem;

  const int tid  = threadIdx.x;
  const int lane = tid & 63;
  const int wave = tid >> 6;          // 0/1 = column half
  const int wn = wave;
  const int q = lane >> 4, m15 = lane & 15;
  const int ibase = by * 64, jbase = bx * 128;

  // fragment read offsets (bytes) for slab s (k=s*32..+31), row-group xg:
  //   row = base + xg*16 + m15 ; chunk = s*2 + (q>>1) ; slot = chunk ^ (row&7)
  //   byte = row*128 + slot*16 + (q&1)*8
  int aoff[4][4], boff[4][4];
#pragma unroll
  for (int s = 0; s < 4; ++s) {
#pragma unroll
    for (int xg = 0; xg < 4; ++xg) {
      int rowA = xg * 16 + m15;                 // full 64 A rows per wave
      aoff[s][xg] = rowA * BK + (((s * 2 + (q >> 1)) ^ (rowA & 7)) * 16) + (q & 1) * 8;
      int rowB = wn * 64 + xg * 16 + m15;       // wave's 64-col B half
      boff[s][xg] = rowB * BK + (((s * 2 + (q >> 1)) ^ (rowB & 7)) * 16) + (q & 1) * 8;
    }
  }

  const int srow = lane >> 3;  // row within 8-row staging group
  const int slot = lane & 7;   // 16B slot within 128B row

  // staging addresses: 4 A-issues + 8 B-issues per wave per slab
  const unsigned char* gA[4];
  const unsigned char* gB[8];
  int lA[4], lB[8];
#pragma unroll
  for (int pp = 0; pp < 4; ++pp) {
    int r0  = wave * 32 + pp * 8;
    int row = r0 + srow;
    int g   = (slot ^ (row & 7)) * 16;
    gA[pp] = embq + (size_t)(ibase + row) * D + g;
    lA[pp] = r0 * BK + (lane << 4);   // base + lane*16 (matches swizzled chunk)
  }
#pragma unroll
  for (int pp = 0; pp < 8; ++pp) {
    int r0  = wave * 64 + pp * 8;
    int row = r0 + srow;
    int g   = (slot ^ (row & 7)) * 16;
    gB[pp] = embq + (size_t)(jbase + row) * D + g;
    lB[pp] = r0 * BK + (lane << 4);
  }

  f32x4 acc[4][4];
  const f32x4 z = {0.f, 0.f, 0.f, 0.f};
#pragma unroll
  for (int a = 0; a < 4; ++a)
#pragma unroll
    for (int b = 0; b < 4; ++b) acc[a][b] = z;

  // prologue: prefetch slab 0 into registers
  uint4 rA[4], rB[8];
#pragma unroll
  for (int pp = 0; pp < 4; ++pp) rA[pp] = *(const uint4*)(gA[pp]);
#pragma unroll
  for (int pp = 0; pp < 8; ++pp) rB[pp] = *(const uint4*)(gB[pp]);

  for (int kb = 0; kb < D; kb += BK) {
    __syncthreads();  // prior iter's ds_reads complete before overwrite
#pragma unroll
    for (int pp = 0; pp < 4; ++pp) *(uint4*)&ldsA[lA[pp]] = rA[pp];
#pragma unroll
    for (int pp = 0; pp < 8; ++pp) *(uint4*)&ldsB[lB[pp]] = rB[pp];
    __syncthreads();  // staged data visible to both waves

    // prefetch next slab into registers (overlaps compute below)
    if (kb + BK < D) {
#pragma unroll
      for (int pp = 0; pp < 4; ++pp) rA[pp] = *(const uint4*)(gA[pp] + kb + BK);
#pragma unroll
      for (int pp = 0; pp < 8; ++pp) rB[pp] = *(const uint4*)(gB[pp] + kb + BK);
    }

#pragma unroll
    for (int s = 0; s < 4; ++s) {
      long af[4];
      long bfr[4];
#pragma unroll
      for (int xg = 0; xg < 4; ++xg) af[xg] = *(const long*)&ldsA[aoff[s][xg]];
#pragma unroll
      for (int xg = 0; xg < 4; ++xg) bfr[xg] = *(const long*)&ldsB[boff[s][xg]];
#pragma unroll
      for (int mi = 0; mi < 4; ++mi)
#pragma unroll
        for (int ni = 0; ni < 4; ++ni)
          acc[mi][ni] = __builtin_amdgcn_mfma_f32_16x16x32_fp8_fp8(
              af[mi], bfr[ni], acc[mi][ni], 0, 0, 0);
    }
  }

  // ---- epilogue (C/D layout: col=lane&15, row=q*4+r) ----
  float sqj[4];
  int labj[4];
#pragma unroll
  for (int ni = 0; ni < 4; ++ni) {
    int jj = jbase + wn * 64 + ni * 16 + m15;
    sqj[ni] = sq[jj];
    labj[ni] = labels[jj];
  }

  ull colBp[4], colBn[4];
#pragma unroll
  for (int ni = 0; ni < 4; ++ni) { colBp[ni] = SENT_P; colBn[ni] = SENT_N; }

#pragma unroll
  for (int mi = 0; mi < 4; ++mi) {
#pragma unroll
    for (int r = 0; r < 4; ++r) {
      const int i = ibase + mi * 16 + q * 4 + r;
      const float si = sq[i];
      const int li = labels[i];
      ull bp = SENT_P;
      ull bn = SENT_N;
#pragma unroll
      for (int ni = 0; ni < 4; ++ni) {
        int jj = jbase + wn * 64 + ni * 16 + m15;
        if (jj > i) {  // strict upper triangle only
          float dot = acc[mi][ni][r];
          float d2 = si + sqj[ni] - 2.0f * dot;
          float dist = sqrtf(fmaxf(d2, 0.0f));
          ull pv = ((ull)__float_as_uint(dist)) << 32;
          if (labj[ni] == li) {
            ull cr = pv | (unsigned)(~jj);  // max -> smallest idx wins ties
            bp = bp > cr ? bp : cr;
            ull cc = pv | (unsigned)(~i);
            colBp[ni] = colBp[ni] > cc ? colBp[ni] : cc;
          } else {
            ull cr = pv | (unsigned)jj;     // min -> smallest idx wins ties
            bn = bn < cr ? bn : cr;
            ull cc = pv | (unsigned)i;
            colBn[ni] = colBn[ni] < cc ? colBn[ni] : cc;
          }
        }
      }
      // row-i reduction across the 16 column lanes (m15 bits); both waves
      // update the same rows via atomics (different col halves) -> merges.
#pragma unroll
      for (int off = 1; off <= 8; off <<= 1) {
        ull op = __shfl_xor(bp, off, 64);
        ull on = __shfl_xor(bn, off, 64);
        bp = bp > op ? bp : op;
        bn = bn < on ? bn : on;
      }
      if (m15 == 0) {
        if (bp != SENT_P) atomicMax(&best_pos[i], bp);
        if (bn != SENT_N) atomicMin(&best_neg[i], bn);
      }
    }
  }

  // col-j reduction across the 4 q lane-groups
#pragma unroll
  for (int ni = 0; ni < 4; ++ni) {
    ull cp = colBp[ni], cn = colBn[ni];
#pragma unroll
    for (int off = 16; off <= 32; off <<= 1) {
      ull op = __shfl_xor(cp, off, 64);
      ull on = __shfl_xor(cn, off, 64);
      cp = cp > op ? cp : op;
      cn = cn < on ? cn : on;
    }
    if (q == 0) {
      int j = jbase + wn * 64 + ni * 16 + m15;
      if (cp != SENT_P) atomicMax(&best_pos[j], cp);
      if (cn != SENT_N) atomicMin(&best_neg[j], cn);
    }
  }
}

// ---------------- loss + finalize in one single-block kernel ----------------
// valid anchor <=> bp != SENT_P && bn != SENT_N. dp/dn from the packed fp32
// dist plus the eps correction:
//   ||x+eps*1||^2 = ||x||^2 + 2 eps (sum_i - sum_j) + D eps^2
__global__ void k_loss_final(const ull* __restrict__ best_pos,
                             const ull* __restrict__ best_neg,
                             const float* __restrict__ rs,
                             float* __restrict__ out) {
  float per = 0.0f;
  int v = 0;
  for (int i = threadIdx.x; i < B; i += 1024) {
    ull bp = best_pos[i], bn = best_neg[i];
    if (bp != SENT_P && bn != SENT_N) {
      unsigned pRaw = ~(unsigned)bp;
      unsigned nRaw = (unsigned)bn;
      int pi = pRaw < (unsigned)B ? (int)pRaw : 0;
      int ni = nRaw < (unsigned)B ? (int)nRaw : 0;
      float distp = __uint_as_float((unsigned)(bp >> 32));
      float distn = __uint_as_float((unsigned)(bn >> 32));
      float ri = rs[i];
      const float e = 1e-6f, de2 = (float)D * 1e-12f;
      float dp2 = distp * distp + 2.0f * e * (ri - rs[pi]) + de2;
      float dn2 = distn * distn + 2.0f * e * (ri - rs[ni]) + de2;
      float dp = sqrtf(fmaxf(dp2, 0.0f));
      float dn = sqrtf(fmaxf(dn2, 0.0f));
      per += fmaxf(dp - dn + 0.3f, 0.0f);
      v += 1;
    }
  }
  for (int off = 32; off; off >>= 1) {
    per += __shfl_down(per, off, 64);
    v   += __shfl_down(v, off, 64);
  }
  __shared__ float pps[16];
  __shared__ int pvs[16];
  int lane = threadIdx.x & 63, wave = threadIdx.x >> 6;
  if (lane == 0) { pps[wave] = per; pvs[wave] = v; }
  __syncthreads();
  if (threadIdx.x == 0) {
    float t = 0.f;
    int cv = 0;
#pragma unroll
    for (int w = 0; w < 16; ++w) { t += pps[w]; cv += pvs[w]; }
    out[0] = cv > 0 ? t / (float)cv : 0.0f;
  }
}

// ---------------- launch -----------------------------------------------------
extern "C" void kernel_launch(void* const* d_in, const int* in_sizes, int n_in,
                              void* d_out, int out_size, void* d_ws, size_t ws_size,
                              hipStream_t stream) {
  const float* emb = (const float*)d_in[0];
  const int* labels = (const int*)d_in[1];
  float* out = (float*)d_out;
  char* ws = (char*)d_ws;

  const size_t off_embq = 0;
  const size_t off_sq   = off_embq + (size_t)B * D;       // 8 MiB
  const size_t off_rs   = off_sq + (size_t)B * 4;
  const size_t off_bp   = off_rs + (size_t)B * 4;
  const size_t off_bn   = off_bp + (size_t)B * 8;

  unsigned char* embq = (unsigned char*)(ws + off_embq);
  float* sq   = (float*)(ws + off_sq);
  float* rs   = (float*)(ws + off_rs);
  ull* bp     = (ull*)(ws + off_bp);
  ull* bn     = (ull*)(ws + off_bn);

  hipLaunchKernelGGL(k_convert_sq, dim3(B), dim3(256), 0, stream,
                     emb, embq, sq, rs, bp, bn);
  hipLaunchKernelGGL(k_gemm_select, dim3(1056), dim3(128), 0, stream,
                     embq, sq, labels, bp, bn);
  hipLaunchKernelGGL(k_loss_final, dim3(1), dim3(1024), 0, stream,
                     bp, bn, rs, out);
}